// Round 10
// baseline (1183.185 us; speedup 1.0000x reference)
//
#include <hip/hip_runtime.h>
#include <stdint.h>

#define BATCH 4096
#define FEAT  40960
#define H1    512
#define KS    4
#define KCHUNK (FEAT / KS)     // 10240
#define NSTEPS (KCHUNK / 32)   // 320 micro (K=32) steps
#define NMACRO (KCHUNK / 128)  // 80 macro (K=128) steps
#define NTILES (FEAT / 32)     // 1280
#define WTILE  32768           // bytes per fragment-major W k-tile
#define WSLOT  32768           // LDS W ring slot (8 waves x 4KB)
#define AOFF   65536           // A tile: 64 rows x 256B (swizzled), 16KB

typedef float f32x4 __attribute__((ext_vector_type(4)));
typedef short s16x8 __attribute__((ext_vector_type(8)));
typedef unsigned int u32x2 __attribute__((ext_vector_type(2)));
typedef unsigned int u32x4 __attribute__((ext_vector_type(4)));

// round-to-nearest-even f32 -> bf16, packed pair (lo in low 16 bits)
__device__ __forceinline__ unsigned bfpack2(float lo, float hi) {
  unsigned a = __float_as_uint(lo);
  unsigned b = __float_as_uint(hi);
  a += 0x7FFFu + ((a >> 16) & 1u);
  b += 0x7FFFu + ((b >> 16) & 1u);
  return (a >> 16) | (b & 0xFFFF0000u);
}

// Swizzle for 64B-row LDS tiles (wcvt image layout), 16B granularity.
__device__ __forceinline__ int lds_swz(int r, int cb) {
  return (r << 6) + (cb ^ (((r >> 1) & 3) << 4));
}

// async global->LDS, 16B per lane; LDS dest = wave-uniform base + lane*16.
__device__ __forceinline__ void glds16(const void* g, void* l) {
  __builtin_amdgcn_global_load_lds(
      (const __attribute__((address_space(1))) unsigned*)g,
      (__attribute__((address_space(3))) unsigned*)l, 16, 0, 0);
}

// ---------------------------------------------------------------------------
// Kernel 0: one-time ftw f32 -> bf16 in FRAGMENT-MAJOR order (unchanged):
// wbf[T][nb][f][lane][8 bf16] — a wave's B-fragment is one contiguous 1KB.
// ---------------------------------------------------------------------------
__global__ __launch_bounds__(512)
void wcvt_kernel(const float* __restrict__ ftw, char* __restrict__ wbf) {
  const int T = blockIdx.x;  // 0..NTILES-1
  const int tid = threadIdx.x;
  const int c  = tid & 7;
  const int r0 = tid >> 3;
#pragma unroll
  for (int pass = 0; pass < 8; ++pass) {
    const int r = pass * 64 + r0;
    const float* src = ftw + (size_t)r * FEAT + T * 32 + c * 4;
    f32x4 v = *(const f32x4*)src;
    u32x2 o;
    o.x = bfpack2(v.x, v.y);
    o.y = bfpack2(v.z, v.w);
    const int nb = r >> 6, f = (r >> 4) & 3, lr = r & 15;
    const int l = (c >> 1) * 16 + lr;
    *(u32x2*)(wbf + (size_t)T * WTILE + ((nb * 4 + f) << 10) + l * 16 +
              (c & 1) * 8) = o;
  }
}

// ---------------------------------------------------------------------------
// Kernel 1: feature-transform GEMM, split-K partials. MACRO-K=128 A STAGING.
// BM=64 BN=512, 512 thr = 8 waves (1M x 8N), wave tile 64x64.
// A: loaded 512B-contiguous per row per wave-instruction (lanes 0-31 = one
//    row's 512B span) -> 4x larger DRAM bursts than the 128B/BK=32 pattern
//    that pinned rounds 5/7/9 at ~2.8 TB/s effective. Single-buffered 16KB
//    swizzled LDS tile; cvt'd mid-macro; 2 barriers per macro (160 total).
// W: unchanged round-9 machinery: fragment-major wbf, per-wave-disjoint
//    2-slot LDS ring, DMA'd 2 micro-steps ahead, counted vmcnt (4/8/4/4).
// LDS 80KB -> 2 blocks/CU, 16 waves/CU.
// ---------------------------------------------------------------------------
__global__ __launch_bounds__(512, 4)
void ft_gemm_kernel(const float* __restrict__ whiteF,
                    const float* __restrict__ blackF,
                    const char* __restrict__ wbf,
                    float* __restrict__ Ppart) {
  __shared__ char smem[81920];  // W slots @0,32768 | A tile @65536 (16KB)

  const int tid = threadIdx.x, bid = blockIdx.x;
  const int wgid = (bid & 7) * 64 + (bid >> 3);  // XCD-chunked, bijective
  const int ks = wgid >> 7;
  const int p  = (wgid >> 6) & 1;
  const int mt = wgid & 63;

  const float* Ag =
      (p == 0 ? whiteF : blackF) + (size_t)(mt * 64) * FEAT + ks * KCHUNK;

  const int lane = tid & 63, wave = tid >> 6;
  const int lrow = lane & 15, lkq = lane >> 4;

  // ---- A staging map: instr j covers rows wave*8 + (lane>>5) + 2j,
  //      f32 cols (lane&31)*4 .. +4 of the macro's 128-col window.
  const int arow = wave * 8 + (lane >> 5);           // + 2j
  const int l31 = lane & 31;
  const float* abase = Ag + (size_t)arow * FEAT + l31 * 4;
  // LDS A write addrs (bf16, swizzled): row stride 256B; 16B chunk c' = c^(r&7)
  int awr[4];
#pragma unroll
  for (int j = 0; j < 4; ++j) {
    const int r = arow + 2 * j;
    awr[j] = AOFF + r * 256 + (((l31 >> 1) ^ (r & 7)) << 4) + (l31 & 1) * 8;
  }
  // LDS A fragment read addrs: frag i row = i*16+lrow; micro m chunk = m*4+lkq
  const int rx7 = lrow & 7;
  int ard[4];
#pragma unroll
  for (int i = 0; i < 4; ++i) ard[i] = AOFF + (i * 16 + lrow) * 256;

  // ---- W: per-wave slice of fragment-major tile image (round-9 machinery)
  const char* wsrc =
      wbf + (size_t)ks * NSTEPS * WTILE + (wave << 12) + lane * 16;
  const int wofs = (wave << 12);  // + slot*WSLOT; frag n at +n*1024+lane*16

  f32x4 acc[4][4];
#pragma unroll
  for (int m = 0; m < 4; ++m)
#pragma unroll
    for (int n = 0; n < 4; ++n) acc[m][n] = (f32x4){0.f, 0.f, 0.f, 0.f};

  f32x4 raf[4];  // A(T+1) f32 in flight (issued micro0, cvt'd micro2)
  u32x2 ab[4];   // A(T+1) bf16, written to LDS at macro end

  // ---- prologue: raf=A(0) [4] ; W(0)->s0 [8] ; W(1)->s1 [12] ; vmcnt(8)
#pragma unroll
  for (int j = 0; j < 4; ++j) raf[j] = *(const f32x4*)(abase + 2 * j * FEAT);
#pragma unroll
  for (int c = 0; c < 4; ++c)
    glds16(wsrc + c * 1024, smem + 0 * WSLOT + wofs + c * 1024);
#pragma unroll
  for (int c = 0; c < 4; ++c)
    glds16(wsrc + WTILE + c * 1024, smem + 1 * WSLOT + wofs + c * 1024);
  asm volatile("s_waitcnt vmcnt(8)" ::: "memory");  // raf done
  __builtin_amdgcn_sched_barrier(0);
#pragma unroll
  for (int j = 0; j < 4; ++j) {
    ab[j].x = bfpack2(raf[j].x, raf[j].y);
    ab[j].y = bfpack2(raf[j].z, raf[j].w);
    *(u32x2*)(smem + awr[j]) = ab[j];
  }
  asm volatile("s_waitcnt lgkmcnt(0)" ::: "memory");
  __builtin_amdgcn_sched_barrier(0);
  __builtin_amdgcn_s_barrier();
  __builtin_amdgcn_sched_barrier(0);
  // steady top-of-macro queue: [W(4T):4, W(4T+1):4] = 8

  // one micro-step: wait WN, optional raf issue / cvt, ds_reads, DMA, MFMA
#define MICRO(M, SLOT, WAITN, DO_RAF, DO_CVT, T)                              \
  {                                                                           \
    asm volatile("s_waitcnt vmcnt(" #WAITN ")" ::: "memory");                 \
    __builtin_amdgcn_sched_barrier(0);                                        \
    if (DO_RAF) {                                                             \
      const int Tn = ((T) + 1 < NMACRO) ? (T) + 1 : NMACRO - 1;               \
      const float* ap = abase + (size_t)Tn * 128;                             \
      _Pragma("unroll") for (int j = 0; j < 4; ++j)                           \
          raf[j] = *(const f32x4*)(ap + 2 * j * FEAT);                        \
    }                                                                         \
    if (DO_CVT) {                                                             \
      _Pragma("unroll") for (int j = 0; j < 4; ++j) {                         \
        ab[j].x = bfpack2(raf[j].x, raf[j].y);                                \
        ab[j].y = bfpack2(raf[j].z, raf[j].w);                                \
      }                                                                       \
    }                                                                         \
    const char* wbase = smem + (SLOT) * WSLOT + wofs;                         \
    s16x8 af[4], wb[4];                                                       \
    _Pragma("unroll") for (int i = 0; i < 4; ++i)                             \
        af[i] = *(const s16x8*)(smem + ard[i] +                               \
                                ((((M) * 4 + lkq) ^ rx7) << 4));              \
    _Pragma("unroll") for (int n = 0; n < 4; ++n)                             \
        wb[n] = *(const s16x8*)(wbase + n * 1024 + lane * 16);                \
    asm volatile("s_waitcnt lgkmcnt(0)" ::: "memory");                        \
    __builtin_amdgcn_sched_barrier(0);                                        \
    { /* DMA W(4T+M+2) into just-freed slot */                                \
      const int u2 = (4 * (T) + (M) + 2 < NSTEPS) ? 4 * (T) + (M) + 2         \
                                                  : NSTEPS - 1;               \
      const char* wsp = wsrc + (size_t)u2 * WTILE;                            \
      char* wdp = smem + (SLOT) * WSLOT + wofs;                               \
      _Pragma("unroll") for (int c = 0; c < 4; ++c)                           \
          glds16(wsp + c * 1024, wdp + c * 1024);                             \
    }                                                                         \
    _Pragma("unroll") for (int n = 0; n < 4; ++n)                             \
      _Pragma("unroll") for (int i = 0; i < 4; ++i)                           \
          acc[i][n] = __builtin_amdgcn_mfma_f32_16x16x32_bf16(                \
              af[i], wb[n], acc[i][n], 0, 0, 0);                              \
  }

  for (int T = 0; T < NMACRO; ++T) {
    MICRO(0, 0, 4, true, false, T);   // completes W(4T);   issues raf, W(4T+2)
    MICRO(1, 1, 8, false, false, T);  // completes W(4T+1); issues W(4T+3)
    MICRO(2, 0, 4, false, true, T);   // completes raf+W(4T+2); cvt; W(4T+4)
    MICRO(3, 1, 4, false, false, T);  // completes W(4T+3); issues W(4T+5)
    // macro end: all reads of A tile done -> barrier, write A(T+1), barrier
    asm volatile("s_waitcnt lgkmcnt(0)" ::: "memory");
    __builtin_amdgcn_sched_barrier(0);
    __builtin_amdgcn_s_barrier();
    __builtin_amdgcn_sched_barrier(0);
#pragma unroll
    for (int j = 0; j < 4; ++j) *(u32x2*)(smem + awr[j]) = ab[j];
    asm volatile("s_waitcnt lgkmcnt(0)" ::: "memory");
    __builtin_amdgcn_sched_barrier(0);
    __builtin_amdgcn_s_barrier();
    __builtin_amdgcn_sched_barrier(0);
  }
#undef MICRO

  // Drain in-flight DMA before epilogue (LDS may be reallocated at endpgm).
  asm volatile("s_waitcnt vmcnt(0) lgkmcnt(0)" ::: "memory");
  __builtin_amdgcn_sched_barrier(0);

  // C/D frag: col = lane&15, row = (lane>>4)*4 + j
  float* Pp = Ppart + ((size_t)(ks * 2 + p) * BATCH + mt * 64) * H1;
  const int r0 = lkq * 4;
  const int c0 = wave * 64 + lrow;
#pragma unroll
  for (int m = 0; m < 4; ++m)
#pragma unroll
    for (int n = 0; n < 4; ++n) {
      float* dst = Pp + (size_t)(r0 + m * 16) * H1 + c0 + n * 16;
#pragma unroll
      for (int j = 0; j < 4; ++j) dst[(size_t)j * H1] = acc[m][n][j];
    }
}

// ---------------------------------------------------------------------------
// Kernel 2: reduce split-K partials + bias + clip[0,1] -> combined bf16
// ---------------------------------------------------------------------------
__global__ __launch_bounds__(256)
void ft_reduce_kernel(const float* __restrict__ Ppart,
                      const float* __restrict__ ftb,
                      unsigned short* __restrict__ comb) {
  const size_t gid = (size_t)blockIdx.x * 256 + threadIdx.x;  // 2*B*H1/4
  const int    pp  = (int)(gid / (BATCH * H1 / 4));
  const size_t rem = gid % (BATCH * H1 / 4);
  const int    row = (int)(rem / (H1 / 4));
  const int    n4  = (int)(rem % (H1 / 4)) * 4;

  f32x4 s = (f32x4){0.f, 0.f, 0.f, 0.f};
#pragma unroll
  for (int ks = 0; ks < KS; ++ks)
    s += *(const f32x4*)(Ppart + ((size_t)(ks * 2 + pp) * BATCH + row) * H1 + n4);
  const f32x4 bv = *(const f32x4*)(ftb + n4);
  s += bv;
  s.x = fminf(fmaxf(s.x, 0.f), 1.f);
  s.y = fminf(fmaxf(s.y, 0.f), 1.f);
  s.z = fminf(fmaxf(s.z, 0.f), 1.f);
  s.w = fminf(fmaxf(s.w, 0.f), 1.f);

  u32x2 o;
  o.x = bfpack2(s.x, s.y);
  o.y = bfpack2(s.z, s.w);
  *(u32x2*)(comb + (size_t)row * 1024 + pp * H1 + n4) = o;
}

// ---------------------------------------------------------------------------
// Kernel 3: fc1 (bf16 MFMA) + relu + fc2 dot + bias -> out FLOAT32 [4096]
// ---------------------------------------------------------------------------
__global__ __launch_bounds__(256)
void fc_kernel(const unsigned short* __restrict__ comb,
               const float* __restrict__ w1, const float* __restrict__ b1,
               const float* __restrict__ w2, const float* __restrict__ b2,
               float* __restrict__ out) {
  __shared__ char smem[40960];  // 2 x (A 4KB + W 16KB)
  __shared__ float rowsum[64];

  const int tid = threadIdx.x;
  const int bm  = blockIdx.x;  // 64 blocks of 64 rows
  if (tid < 64) rowsum[tid] = 0.f;

  const int a_row = tid >> 2, a_kq = tid & 3;
  const unsigned short* aptr = comb + (size_t)(bm * 64 + a_row) * 1024 + a_kq * 8;
  const float* wptr = w1 + (size_t)a_row * 1024 + a_kq * 8;

  u32x4 raA;
  f32x4 rw0[4], rw1[4];
  auto issue = [&](int t) {
    raA = *(const u32x4*)(aptr + t * 32);
    const float* wp = wptr + t * 32;
#pragma unroll
    for (int s = 0; s < 4; ++s) {
      rw0[s] = *(const f32x4*)(wp + (size_t)s * 64 * 1024);
      rw1[s] = *(const f32x4*)(wp + (size_t)s * 64 * 1024 + 4);
    }
  };

  const int aoff_w = lds_swz(a_row, a_kq * 16);
  int woff_w[4];
#pragma unroll
  for (int s = 0; s < 4; ++s)
    woff_w[s] = 4096 + lds_swz(s * 64 + a_row, a_kq * 16);

  auto cvtwrite = [&](int b) {
    char* base = smem + b * 20480;
    *(u32x4*)(base + aoff_w) = raA;
#pragma unroll
    for (int s = 0; s < 4; ++s) {
      u32x4 wv;
      wv.x = bfpack2(rw0[s].x, rw0[s].y); wv.y = bfpack2(rw0[s].z, rw0[s].w);
      wv.z = bfpack2(rw1[s].x, rw1[s].y); wv.w = bfpack2(rw1[s].z, rw1[s].w);
      *(u32x4*)(base + woff_w[s]) = wv;
    }
  };

  const int lane = tid & 63, wn = tid >> 6;
  const int lrow = lane & 15, lkb = (lane >> 4) * 16;
  int a_off[4], b_off[4];
#pragma unroll
  for (int m = 0; m < 4; ++m) a_off[m] = lds_swz(m * 16 + lrow, lkb);
#pragma unroll
  for (int n = 0; n < 4; ++n) b_off[n] = 4096 + lds_swz(wn * 64 + n * 16 + lrow, lkb);

  f32x4 acc[4][4];
#pragma unroll
  for (int m = 0; m < 4; ++m)
#pragma unroll
    for (int n = 0; n < 4; ++n) acc[m][n] = (f32x4){0.f, 0.f, 0.f, 0.f};

  issue(0);
  for (int t = 0; t < 32; ++t) {
    const int b = t & 1;
    cvtwrite(b);
    if (t + 1 < 32) issue(t + 1);
    asm volatile("s_waitcnt lgkmcnt(0)" ::: "memory");
    __builtin_amdgcn_sched_barrier(0);
    __builtin_amdgcn_s_barrier();
    __builtin_amdgcn_sched_barrier(0);
    char* base = smem + b * 20480;
    s16x8 af[4];
#pragma unroll
    for (int m = 0; m < 4; ++m) af[m] = *(const s16x8*)(base + a_off[m]);
#pragma unroll
    for (int n = 0; n < 4; ++n) {
      s16x8 bfn = *(const s16x8*)(base + b_off[n]);
#pragma unroll
      for (int m = 0; m < 4; ++m)
        acc[m][n] = __builtin_amdgcn_mfma_f32_16x16x32_bf16(af[m], bfn, acc[m][n], 0, 0, 0);
    }
  }

  float b1v[4], w2v[4];
#pragma unroll
  for (int n = 0; n < 4; ++n) {
    const int col = wn * 64 + n * 16 + lrow;
    b1v[n] = b1[col];
    w2v[n] = w2[col];
  }
#pragma unroll
  for (int m = 0; m < 4; ++m)
#pragma unroll
    for (int j = 0; j < 4; ++j) {
      float v = 0.f;
#pragma unroll
      for (int n = 0; n < 4; ++n) {
        float x = acc[m][n][j] + b1v[n];
        x = fmaxf(x, 0.f);
        v += x * w2v[n];
      }
#pragma unroll
      for (int d = 1; d < 16; d <<= 1) v += __shfl_xor(v, d, 64);
      if ((lane & 15) == 0)
        atomicAdd(&rowsum[m * 16 + (lane >> 4) * 4 + j], v);
    }
  __syncthreads();
  if (tid < 64) {
    out[bm * 64 + tid] = rowsum[tid] + b2[0];  // f32 output
  }
}

// ---------------------------------------------------------------------------
extern "C" void kernel_launch(void* const* d_in, const int* in_sizes, int n_in,
                              void* d_out, int out_size, void* d_ws, size_t ws_size,
                              hipStream_t stream) {
  const float* whiteF = (const float*)d_in[0];
  const float* blackF = (const float*)d_in[1];
  const float* ftw    = (const float*)d_in[2];
  const float* ftb    = (const float*)d_in[3];
  const float* w1     = (const float*)d_in[4];
  const float* b1     = (const float*)d_in[5];
  const float* w2     = (const float*)d_in[6];
  const float* b2     = (const float*)d_in[7];

  char* wbf = (char*)d_ws;                                   // 41,943,040 B
  const size_t wbf_bytes   = (size_t)NTILES * WTILE;
  const size_t ppart_bytes = (size_t)KS * 2 * BATCH * H1 * sizeof(float);
  float* Ppart = (float*)((char*)d_ws + wbf_bytes);
  unsigned short* comb = (unsigned short*)((char*)d_ws + wbf_bytes + ppart_bytes);
  float* outp = (float*)d_out;

  hipLaunchKernelGGL(wcvt_kernel, dim3(NTILES), dim3(512), 0, stream, ftw, wbf);
  hipLaunchKernelGGL(ft_gemm_kernel, dim3(512), dim3(512), 0, stream,
                     whiteF, blackF, wbf, Ppart);
  hipLaunchKernelGGL(ft_reduce_kernel, dim3((2 * BATCH * H1 / 4) / 256), dim3(256),
                     0, stream, Ppart, ftb, comb);
  hipLaunchKernelGGL(fc_kernel, dim3(BATCH / 64), dim3(256), 0, stream,
                     comb, w1, b1, w2, b2, outp);
}

// Round 11
// 772.647 us; speedup vs baseline: 1.5313x; 1.5313x over previous
//
#include <hip/hip_runtime.h>
#include <stdint.h>

#define BATCH 4096
#define FEAT  40960
#define H1    512
#define KS    4
#define KCHUNK (FEAT / KS)    // 10240
#define NSTEPS (KCHUNK / 32)  // 320
#define NTILES (FEAT / 32)    // 1280
#define WTILE  32768          // bytes per fragment-major W k-tile
#define WSLOT  8192           // LDS W ring slot (4 waves x 2KB)
#define ABASE  16384          // A slots: 2 x 4KB @ 16384, 20480

typedef float f32x4 __attribute__((ext_vector_type(4)));
typedef short s16x8 __attribute__((ext_vector_type(8)));
typedef unsigned int u32x2 __attribute__((ext_vector_type(2)));
typedef unsigned int u32x4 __attribute__((ext_vector_type(4)));

// round-to-nearest-even f32 -> bf16, packed pair (lo in low 16 bits)
__device__ __forceinline__ unsigned bfpack2(float lo, float hi) {
  unsigned a = __float_as_uint(lo);
  unsigned b = __float_as_uint(hi);
  a += 0x7FFFu + ((a >> 16) & 1u);
  b += 0x7FFFu + ((b >> 16) & 1u);
  return (a >> 16) | (b & 0xFFFF0000u);
}

// Swizzle for 64B-row LDS tiles (A staging), 16B granularity; 2-way = free.
__device__ __forceinline__ int lds_swz(int r, int cb) {
  return (r << 6) + (cb ^ (((r >> 1) & 3) << 4));
}

// async global->LDS, 16B per lane; LDS dest = wave-uniform base + lane*16.
__device__ __forceinline__ void glds16(const void* g, void* l) {
  __builtin_amdgcn_global_load_lds(
      (const __attribute__((address_space(1))) unsigned*)g,
      (__attribute__((address_space(3))) unsigned*)l, 16, 0, 0);
}

// ---------------------------------------------------------------------------
// Kernel 0: one-time ftw f32 -> bf16 in FRAGMENT-MAJOR order (unchanged):
// wbf[T][cb][lane][8 bf16], cb = row/16 — a 16-col fragment is contiguous 1KB.
// ---------------------------------------------------------------------------
__global__ __launch_bounds__(512)
void wcvt_kernel(const float* __restrict__ ftw, char* __restrict__ wbf) {
  const int T = blockIdx.x;  // 0..NTILES-1
  const int tid = threadIdx.x;
  const int c  = tid & 7;
  const int r0 = tid >> 3;
#pragma unroll
  for (int pass = 0; pass < 8; ++pass) {
    const int r = pass * 64 + r0;
    const float* src = ftw + (size_t)r * FEAT + T * 32 + c * 4;
    f32x4 v = *(const f32x4*)src;
    u32x2 o;
    o.x = bfpack2(v.x, v.y);
    o.y = bfpack2(v.z, v.w);
    const int cb = r >> 4, lr = r & 15;
    const int l = (c >> 1) * 16 + lr;
    *(u32x2*)(wbf + (size_t)T * WTILE + (cb << 10) + l * 16 + (c & 1) * 8) = o;
  }
}

// ---------------------------------------------------------------------------
// Kernel 1: feature-transform GEMM, split-K partials. SMALL-BLOCK / HIGH-TLP.
// Block: 256 thr = 4 waves (1M x 4N), tile 64x128, wave tile 64x32,
// acc[4][2] = 32 AGPR. LDS 24KB (W ring 2x8KB + A 2x4KB) -> 6 blocks/CU,
// 24 waves/CU: 3x more independent latency chains than the 511us plateau.
// W: per-wave-disjoint 2KB slices of fragment-major wbf, ring-of-2, DMA'd
//    2 steps ahead, counted vmcnt(4) at step top (never drained mid-loop).
// A: cooperative coalesced stage (read once), cvt 1 step ahead, 1 barrier/step.
// Grid 2048; XCD map: xcd=bid&7 -> (p,ks); the 4 N-twins sharing A rows are
// adjacent in time on the same XCD so twin A re-reads hit that XCD's L2.
// ---------------------------------------------------------------------------
__global__ __launch_bounds__(256, 6)
void ft_gemm_kernel(const float* __restrict__ whiteF,
                    const float* __restrict__ blackF,
                    const char* __restrict__ wbf,
                    float* __restrict__ Ppart) {
  __shared__ char smem[24576];  // W slots @0,8192 | A slots @16384,20480

  const int tid = threadIdx.x, bid = blockIdx.x;
  const int xcd = bid & 7, idx = bid >> 3;
  const int p  = xcd & 1;          // perspective
  const int ks = xcd >> 1;         // 0..3
  const int nt = idx & 3;          // N-tile (128 cols)
  const int mt = idx >> 2;         // m-tile (64 rows)

  const float* Ag =
      (p == 0 ? whiteF : blackF) + (size_t)(mt * 64) * FEAT + ks * KCHUNK;

  // A staging: 64 rows x 4 threads/row x 8 f32 (128B contiguous per row)
  const int a_row = tid >> 2, a_kc = tid & 3;
  const float* aptr = Ag + (size_t)a_row * FEAT + a_kc * 8;
  const int awoff = lds_swz(a_row, a_kc * 16);  // + ABASE + slot*4096

  const int lane = tid & 63, wn = tid >> 6;
  const int lrow = lane & 15, lkq = lane >> 4;

  // W: wave's 32-col slice = 2 contiguous 1KB fragments at chunk cb, cb+1
  const int cb = (nt * 4 + wn) * 2;
  const char* wsrc = wbf + (size_t)ks * NSTEPS * WTILE + (cb << 10) + lane * 16;
  const int wofs = wn * 2048;  // + slot*WSLOT; frag n at +n*1024+lane*16

  int a_off[4];
#pragma unroll
  for (int m = 0; m < 4; ++m) a_off[m] = lds_swz(m * 16 + lrow, lkq * 16);

  f32x4 acc[4][2];
#pragma unroll
  for (int m = 0; m < 4; ++m)
#pragma unroll
    for (int n = 0; n < 2; ++n) acc[m][n] = (f32x4){0.f, 0.f, 0.f, 0.f};

  f32x4 raA0, raA1;  // A(t+1) f32 (8 f32), issued step t, cvt'd step t+1... 1-ahead

  // ---- prologue: A(0):2 (oldest), W(0)->s0:2, W(1)->s1:2
  raA0 = *(const f32x4*)aptr;
  raA1 = *(const f32x4*)(aptr + 4);
#pragma unroll
  for (int c = 0; c < 2; ++c)
    glds16(wsrc + c * 1024, smem + 0 * WSLOT + wofs + c * 1024);
#pragma unroll
  for (int c = 0; c < 2; ++c)
    glds16(wsrc + WTILE + c * 1024, smem + 1 * WSLOT + wofs + c * 1024);
  {  // cvt A(0) (auto-wait drains only A: it is the oldest) -> slot 0
    u32x4 av;
    av.x = bfpack2(raA0.x, raA0.y); av.y = bfpack2(raA0.z, raA0.w);
    av.z = bfpack2(raA1.x, raA1.y); av.w = bfpack2(raA1.z, raA1.w);
    *(u32x4*)(smem + ABASE + 0 * 4096 + awoff) = av;
  }
  raA0 = *(const f32x4*)(aptr + 32);  // A(1)
  raA1 = *(const f32x4*)(aptr + 36);
  asm volatile("s_waitcnt lgkmcnt(0)" ::: "memory");
  __builtin_amdgcn_sched_barrier(0);
  __builtin_amdgcn_s_barrier();
  __builtin_amdgcn_sched_barrier(0);
  // steady top-of-step queue: [W(t):2, A(t+1):2, W(t+1):2] = 6

#define GSTEP(B, t)                                                           \
  {                                                                           \
    asm volatile("s_waitcnt vmcnt(4)" ::: "memory"); /* W(t) landed */        \
    __builtin_amdgcn_sched_barrier(0);                                        \
    const char* wbase = smem + (B) * WSLOT + wofs;                            \
    const char* abase = smem + ABASE + (B) * 4096;                            \
    s16x8 af[4], wb[2];                                                       \
    _Pragma("unroll") for (int m = 0; m < 4; ++m)                             \
        af[m] = *(const s16x8*)(abase + a_off[m]);                            \
    _Pragma("unroll") for (int n = 0; n < 2; ++n)                             \
        wb[n] = *(const s16x8*)(wbase + n * 1024 + lane * 16);                \
    asm volatile("s_waitcnt lgkmcnt(0)" ::: "memory"); /* reads landed */     \
    __builtin_amdgcn_sched_barrier(0);                                        \
    { /* cvt A(t+1) (auto-wait drains only A) -> slot B^1 */                  \
      u32x4 av;                                                               \
      av.x = bfpack2(raA0.x, raA0.y); av.y = bfpack2(raA0.z, raA0.w);         \
      av.z = bfpack2(raA1.x, raA1.y); av.w = bfpack2(raA1.z, raA1.w);         \
      *(u32x4*)(smem + ABASE + ((B) ^ 1) * 4096 + awoff) = av;                \
    }                                                                         \
    { /* issue A(t+2) BEFORE W(t+2) so next cvt's auto-wait spares W */       \
      const int t2 = ((t) + 2 < NSTEPS) ? (t) + 2 : NSTEPS - 1;               \
      raA0 = *(const f32x4*)(aptr + (size_t)t2 * 32);                         \
      raA1 = *(const f32x4*)(aptr + (size_t)t2 * 32 + 4);                     \
      const char* wsp = wsrc + (size_t)t2 * WTILE;                            \
      char* wdp = smem + (B) * WSLOT + wofs;                                  \
      _Pragma("unroll") for (int c = 0; c < 2; ++c)                           \
          glds16(wsp + c * 1024, wdp + c * 1024);                             \
    }                                                                         \
    _Pragma("unroll") for (int n = 0; n < 2; ++n)                             \
      _Pragma("unroll") for (int m = 0; m < 4; ++m)                           \
          acc[m][n] = __builtin_amdgcn_mfma_f32_16x16x32_bf16(                \
              af[m], wb[n], acc[m][n], 0, 0, 0);                              \
    asm volatile("s_waitcnt lgkmcnt(0)" ::: "memory"); /* A-write visible */  \
    __builtin_amdgcn_sched_barrier(0);                                        \
    __builtin_amdgcn_s_barrier();                                             \
    __builtin_amdgcn_sched_barrier(0);                                        \
  }

  for (int tt = 0; tt < NSTEPS; tt += 2) {
    GSTEP(0, tt);
    GSTEP(1, tt + 1);
  }
#undef GSTEP

  // Drain in-flight DMA before epilogue (LDS may be reallocated at endpgm).
  asm volatile("s_waitcnt vmcnt(0) lgkmcnt(0)" ::: "memory");
  __builtin_amdgcn_sched_barrier(0);

  // C/D frag: col = lane&15, row = (lane>>4)*4 + j
  float* Pp = Ppart + ((size_t)(ks * 2 + p) * BATCH + mt * 64) * H1;
  const int r0 = lkq * 4;
  const int c0 = nt * 128 + wn * 32 + lrow;
#pragma unroll
  for (int m = 0; m < 4; ++m)
#pragma unroll
    for (int n = 0; n < 2; ++n) {
      float* dst = Pp + (size_t)(r0 + m * 16) * H1 + c0 + n * 16;
#pragma unroll
      for (int j = 0; j < 4; ++j) dst[(size_t)j * H1] = acc[m][n][j];
    }
}

// ---------------------------------------------------------------------------
// Kernel 2: reduce split-K partials + bias + clip[0,1] -> combined bf16
// ---------------------------------------------------------------------------
__global__ __launch_bounds__(256)
void ft_reduce_kernel(const float* __restrict__ Ppart,
                      const float* __restrict__ ftb,
                      unsigned short* __restrict__ comb) {
  const size_t gid = (size_t)blockIdx.x * 256 + threadIdx.x;  // 2*B*H1/4
  const int    pp  = (int)(gid / (BATCH * H1 / 4));
  const size_t rem = gid % (BATCH * H1 / 4);
  const int    row = (int)(rem / (H1 / 4));
  const int    n4  = (int)(rem % (H1 / 4)) * 4;

  f32x4 s = (f32x4){0.f, 0.f, 0.f, 0.f};
#pragma unroll
  for (int ks = 0; ks < KS; ++ks)
    s += *(const f32x4*)(Ppart + ((size_t)(ks * 2 + pp) * BATCH + row) * H1 + n4);
  const f32x4 bv = *(const f32x4*)(ftb + n4);
  s += bv;
  s.x = fminf(fmaxf(s.x, 0.f), 1.f);
  s.y = fminf(fmaxf(s.y, 0.f), 1.f);
  s.z = fminf(fmaxf(s.z, 0.f), 1.f);
  s.w = fminf(fmaxf(s.w, 0.f), 1.f);

  u32x2 o;
  o.x = bfpack2(s.x, s.y);
  o.y = bfpack2(s.z, s.w);
  *(u32x2*)(comb + (size_t)row * 1024 + pp * H1 + n4) = o;
}

// ---------------------------------------------------------------------------
// Kernel 3: fc1 (bf16 MFMA) + relu + fc2 dot + bias -> out FLOAT32 [4096]
// ---------------------------------------------------------------------------
__global__ __launch_bounds__(256)
void fc_kernel(const unsigned short* __restrict__ comb,
               const float* __restrict__ w1, const float* __restrict__ b1,
               const float* __restrict__ w2, const float* __restrict__ b2,
               float* __restrict__ out) {
  __shared__ char smem[40960];  // 2 x (A 4KB + W 16KB)
  __shared__ float rowsum[64];

  const int tid = threadIdx.x;
  const int bm  = blockIdx.x;  // 64 blocks of 64 rows
  if (tid < 64) rowsum[tid] = 0.f;

  const int a_row = tid >> 2, a_kq = tid & 3;
  const unsigned short* aptr = comb + (size_t)(bm * 64 + a_row) * 1024 + a_kq * 8;
  const float* wptr = w1 + (size_t)a_row * 1024 + a_kq * 8;

  u32x4 raA;
  f32x4 rw0[4], rw1[4];
  auto issue = [&](int t) {
    raA = *(const u32x4*)(aptr + t * 32);
    const float* wp = wptr + t * 32;
#pragma unroll
    for (int s = 0; s < 4; ++s) {
      rw0[s] = *(const f32x4*)(wp + (size_t)s * 64 * 1024);
      rw1[s] = *(const f32x4*)(wp + (size_t)s * 64 * 1024 + 4);
    }
  };

  const int aoff_w = lds_swz(a_row, a_kq * 16);
  int woff_w[4];
#pragma unroll
  for (int s = 0; s < 4; ++s)
    woff_w[s] = 4096 + lds_swz(s * 64 + a_row, a_kq * 16);

  auto cvtwrite = [&](int b) {
    char* base = smem + b * 20480;
    *(u32x4*)(base + aoff_w) = raA;
#pragma unroll
    for (int s = 0; s < 4; ++s) {
      u32x4 wv;
      wv.x = bfpack2(rw0[s].x, rw0[s].y); wv.y = bfpack2(rw0[s].z, rw0[s].w);
      wv.z = bfpack2(rw1[s].x, rw1[s].y); wv.w = bfpack2(rw1[s].z, rw1[s].w);
      *(u32x4*)(base + woff_w[s]) = wv;
    }
  };

  const int lane = tid & 63, wn = tid >> 6;
  const int lrow = lane & 15, lkb = (lane >> 4) * 16;
  int a_off[4], b_off[4];
#pragma unroll
  for (int m = 0; m < 4; ++m) a_off[m] = lds_swz(m * 16 + lrow, lkb);
#pragma unroll
  for (int n = 0; n < 4; ++n) b_off[n] = 4096 + lds_swz(wn * 64 + n * 16 + lrow, lkb);

  f32x4 acc[4][4];
#pragma unroll
  for (int m = 0; m < 4; ++m)
#pragma unroll
    for (int n = 0; n < 4; ++n) acc[m][n] = (f32x4){0.f, 0.f, 0.f, 0.f};

  issue(0);
  for (int t = 0; t < 32; ++t) {
    const int b = t & 1;
    cvtwrite(b);
    if (t + 1 < 32) issue(t + 1);
    asm volatile("s_waitcnt lgkmcnt(0)" ::: "memory");
    __builtin_amdgcn_sched_barrier(0);
    __builtin_amdgcn_s_barrier();
    __builtin_amdgcn_sched_barrier(0);
    char* base = smem + b * 20480;
    s16x8 af[4];
#pragma unroll
    for (int m = 0; m < 4; ++m) af[m] = *(const s16x8*)(base + a_off[m]);
#pragma unroll
    for (int n = 0; n < 4; ++n) {
      s16x8 bfn = *(const s16x8*)(base + b_off[n]);
#pragma unroll
      for (int m = 0; m < 4; ++m)
        acc[m][n] = __builtin_amdgcn_mfma_f32_16x16x32_bf16(af[m], bfn, acc[m][n], 0, 0, 0);
    }
  }

  float b1v[4], w2v[4];
#pragma unroll
  for (int n = 0; n < 4; ++n) {
    const int col = wn * 64 + n * 16 + lrow;
    b1v[n] = b1[col];
    w2v[n] = w2[col];
  }
#pragma unroll
  for (int m = 0; m < 4; ++m)
#pragma unroll
    for (int j = 0; j < 4; ++j) {
      float v = 0.f;
#pragma unroll
      for (int n = 0; n < 4; ++n) {
        float x = acc[m][n][j] + b1v[n];
        x = fmaxf(x, 0.f);
        v += x * w2v[n];
      }
#pragma unroll
      for (int d = 1; d < 16; d <<= 1) v += __shfl_xor(v, d, 64);
      if ((lane & 15) == 0)
        atomicAdd(&rowsum[m * 16 + (lane >> 4) * 4 + j], v);
    }
  __syncthreads();
  if (tid < 64) {
    out[bm * 64 + tid] = rowsum[tid] + b2[0];  // f32 output
  }
}

// ---------------------------------------------------------------------------
extern "C" void kernel_launch(void* const* d_in, const int* in_sizes, int n_in,
                              void* d_out, int out_size, void* d_ws, size_t ws_size,
                              hipStream_t stream) {
  const float* whiteF = (const float*)d_in[0];
  const float* blackF = (const float*)d_in[1];
  const float* ftw    = (const float*)d_in[2];
  const float* ftb    = (const float*)d_in[3];
  const float* w1     = (const float*)d_in[4];
  const float* b1     = (const float*)d_in[5];
  const float* w2     = (const float*)d_in[6];
  const float* b2     = (const float*)d_in[7];

  char* wbf = (char*)d_ws;                                   // 41,943,040 B
  const size_t wbf_bytes   = (size_t)NTILES * WTILE;
  const size_t ppart_bytes = (size_t)KS * 2 * BATCH * H1 * sizeof(float);
  float* Ppart = (float*)((char*)d_ws + wbf_bytes);
  unsigned short* comb = (unsigned short*)((char*)d_ws + wbf_bytes + ppart_bytes);
  float* outp = (float*)d_out;

  hipLaunchKernelGGL(wcvt_kernel, dim3(NTILES), dim3(512), 0, stream, ftw, wbf);
  hipLaunchKernelGGL(ft_gemm_kernel, dim3(2048), dim3(256), 0, stream,
                     whiteF, blackF, wbf, Ppart);
  hipLaunchKernelGGL(ft_reduce_kernel, dim3((2 * BATCH * H1 / 4) / 256), dim3(256),
                     0, stream, Ppart, ftb, comb);
  hipLaunchKernelGGL(fc_kernel, dim3(BATCH / 64), dim3(256), 0, stream,
                     comb, w1, b1, w2, b2, outp);
}